// Round 7
// baseline (572.927 us; speedup 1.0000x reference)
//
#include <hip/hip_runtime.h>
#include <hip/hip_bf16.h>

typedef __bf16 bf16x8 __attribute__((ext_vector_type(8)));
typedef float  f32x4  __attribute__((ext_vector_type(4)));
typedef unsigned short u16;
typedef unsigned short u16x4 __attribute__((ext_vector_type(4)));
typedef unsigned long long u64;

#define NB 1024
#define NS 1024
#define NI 32
#define NH 128

__device__ __forceinline__ u64 pack4_bf16(f32x4 v) {
  u16x4 p;
#pragma unroll
  for (int r = 0; r < 4; ++r) p[r] = __builtin_bit_cast(u16, (__bf16)v[r]);
  return __builtin_bit_cast(u64, p);
}

// Barrier that drains lgkmcnt only (no vmcnt): global stores stay in flight.
__device__ __forceinline__ void lds_barrier() {
  __builtin_amdgcn_sched_barrier(0);
  asm volatile("s_waitcnt lgkmcnt(0)" ::: "memory");
  __builtin_amdgcn_s_barrier();
  asm volatile("" ::: "memory");
  __builtin_amdgcn_sched_barrier(0);
}

// Fused gate math, 3 trans ops per element (2 exp2 + 1 shared rcp):
//   z·(hh−h) = [(f−1) − h(f+1)] / [(1+e)(f+1)],  e = e^{−az}, f = e^{2·ah}
// az/ah clamped to ±15: clamp error ≤3e-7; den ≤ 2^65 (no overflow).
__device__ __forceinline__ f32x4 gru_elem(f32x4 az, f32x4 ah, f32x4 h) {
  const float NL2E  = -1.4426950408889634f;  // -log2(e)
  const float P2L2E =  2.8853900817779268f;  //  2*log2(e)
  f32x4 hn;
#pragma unroll
  for (int r = 0; r < 4; ++r) {
    float a  = fminf(15.f, fmaxf(-15.f, az[r]));
    float b  = fminf(15.f, fmaxf(-15.f, ah[r]));
    float e  = __builtin_amdgcn_exp2f(a * NL2E);
    float f  = __builtin_amdgcn_exp2f(b * P2L2E);
    float fp = f + 1.f;
    float num = __builtin_fmaf(-h[r], fp, f - 1.f);
    float den = (1.f + e) * fp;
    float rr  = __builtin_amdgcn_rcpf(den);
    hn[r] = __builtin_fmaf(num, rr, h[r]);
  }
  return hn;
}

// Block: 256 threads = 4 waves (1/SIMD). Block owns 16 batch rows for the whole scan.
// Wave w computes hidden cols [32w, 32w+32) (2 n-tiles). Fewer waves = half the
// per-step LDS broadcast (each wave must read the FULL h tile as MFMA B-operand).
// MFMA: D'[n][m] = sum_k U[k][n] * h[m][k]  (A' = U^T slice, B' = h^T)
//   B'-frag: lane l holds h[m=l&15][k = 32kt + 8(l>>4) + j]   (one ds_read_b128)
//   D'     : lane l holds h_new[m=l&15][n = 32w + 16nt + 4(l>>4) + r]
// LDS k-major + 17-row pad: b128 reads are bank-uniform (8 lanes/quad = floor).
__global__ __launch_bounds__(256, 1) void gru_scan(
    const float* __restrict__ x,
    const float* __restrict__ Wz, const float* __restrict__ Uz, const float* __restrict__ bz,
    const float* __restrict__ Wh, const float* __restrict__ Uh, const float* __restrict__ bh,
    float* __restrict__ out)
{
  __shared__ __align__(16) u64 hb[2][16][17][2];       // 8.5 KB
  __shared__ __align__(16) u64 hx[2][8][4][17][2];     // 17 KB

  const int tid  = threadIdx.x;
  const int lane = tid & 63;
  const int w    = tid >> 6;     // wave 0..3
  const int ml   = lane & 15;    // batch row in tile
  const int g    = lane >> 4;    // k-group / reg-group
  const int rb   = blockIdx.x * 16;

  // ---- persistent weight fragments (2 n-tiles per wave) ----
  bf16x8 ufrag[2][2][4];   // [gate][nt][kt]
  bf16x8 wfrag[2][2];      // [gate][nt]
  f32x4  bias2[2][2];      // [gate][nt], D layout
  {
    const float* Ug[2] = {Uz, Uh};
    const float* Wg[2] = {Wz, Wh};
    const float* bg[2] = {bz, bh};
#pragma unroll
    for (int gate = 0; gate < 2; ++gate) {
#pragma unroll
      for (int nt = 0; nt < 2; ++nt) {
        const int n0 = 32 * w + 16 * nt + ml;   // A'-row = hidden col
#pragma unroll
        for (int kt = 0; kt < 4; ++kt)
#pragma unroll
          for (int j = 0; j < 8; ++j)
            ufrag[gate][nt][kt][j] = (__bf16)Ug[gate][(32 * kt + 8 * g + j) * NH + n0];
#pragma unroll
        for (int j = 0; j < 8; ++j)
          wfrag[gate][nt][j] = (__bf16)Wg[gate][(8 * g + j) * NH + n0];
        const int nb = 32 * w + 16 * nt + 4 * g;
#pragma unroll
        for (int r = 0; r < 4; ++r) bias2[gate][nt][r] = bg[gate][nb + r];
      }
    }
  }

  // h0 = 0
  for (int i = tid; i < 16 * 17 * 2; i += 256) ((u64*)hb[0])[i] = 0ULL;

  // ---- x staging: thread (r_st, c16) handles 16 floats = 2 bf16x8 units per chunk ----
  const int r_st  = tid >> 4;          // 0..15
  const int c16   = tid & 15;          // tt = c16>>1, half = c16&1
  const int tt_st = c16 >> 1;
  const int ku0   = (c16 & 1) * 2;
  const float* xbase = x + (size_t)(rb + r_st) * (NS * NI) + tt_st * NI + (c16 & 1) * 16;

  {  // stage chunk 0
    f32x4 a0 = *(const f32x4*)(xbase);
    f32x4 a1 = *(const f32x4*)(xbase + 4);
    f32x4 a2 = *(const f32x4*)(xbase + 8);
    f32x4 a3 = *(const f32x4*)(xbase + 12);
    bf16x8 u0, u1;
#pragma unroll
    for (int j = 0; j < 4; ++j) {
      u0[j] = (__bf16)a0[j]; u0[4 + j] = (__bf16)a1[j];
      u1[j] = (__bf16)a2[j]; u1[4 + j] = (__bf16)a3[j];
    }
    *(bf16x8*)&hx[0][tt_st][ku0 + 0][r_st][0] = u0;
    *(bf16x8*)&hx[0][tt_st][ku0 + 1][r_st][0] = u1;
  }
  __syncthreads();   // cold path: full drain fine

  f32x4 hv0 = {0.f, 0.f, 0.f, 0.f};
  f32x4 hv1 = {0.f, 0.f, 0.f, 0.f};
  float* optr = out + (size_t)(rb + ml) * NS * NH + 32 * w + 4 * g;

  f32x4 vx0, vx1, vx2, vx3;   // x global prefetch
  const f32x4 zero4 = {0.f, 0.f, 0.f, 0.f};

  // ax (= bias + x@W) for t = 0
  f32x4 axz0, axz1, axh0, axh1;
  {
    bf16x8 xf = *(const bf16x8*)&hx[0][0][g][ml][0];
    axz0 = __builtin_amdgcn_mfma_f32_16x16x32_bf16(wfrag[0][0], xf, bias2[0][0], 0, 0, 0);
    axz1 = __builtin_amdgcn_mfma_f32_16x16x32_bf16(wfrag[0][1], xf, bias2[0][1], 0, 0, 0);
    axh0 = __builtin_amdgcn_mfma_f32_16x16x32_bf16(wfrag[1][0], xf, bias2[1][0], 0, 0, 0);
    axh1 = __builtin_amdgcn_mfma_f32_16x16x32_bf16(wfrag[1][1], xf, bias2[1][1], 0, 0, 0);
  }

  // One step. P = t&1 compile-time. Consumes ax(t); produces ax(t+1).
#define GRU_STEP(P, XB, TT)                                                                 \
  {                                                                                         \
    /* post-barrier read burst: 4 h frags + 1 x frag, all bank-uniform */                   \
    bf16x8 hf0 = *(const bf16x8*)&hb[P][ 0 + g][ml][0];                                     \
    bf16x8 hf1 = *(const bf16x8*)&hb[P][ 4 + g][ml][0];                                     \
    bf16x8 hf2 = *(const bf16x8*)&hb[P][ 8 + g][ml][0];                                     \
    bf16x8 hf3 = *(const bf16x8*)&hb[P][12 + g][ml][0];                                     \
    const int nxb = ((TT) == 7) ? (XB) ^ 1 : (XB);                                          \
    const int ntt = ((TT) + 1) & 7;                                                         \
    bf16x8 xf = *(const bf16x8*)&hx[nxb][ntt][g][ml][0];                                    \
    /* h-MFMAs: 8 independent 2-deep chains (2 gates x 2 n-tiles x 2 halves) */             \
    f32x4 cz0a = __builtin_amdgcn_mfma_f32_16x16x32_bf16(ufrag[0][0][0], hf0, axz0, 0,0,0); \
    f32x4 cz1a = __builtin_amdgcn_mfma_f32_16x16x32_bf16(ufrag[0][1][0], hf0, axz1, 0,0,0); \
    f32x4 ch0a = __builtin_amdgcn_mfma_f32_16x16x32_bf16(ufrag[1][0][0], hf0, axh0, 0,0,0); \
    f32x4 ch1a = __builtin_amdgcn_mfma_f32_16x16x32_bf16(ufrag[1][1][0], hf0, axh1, 0,0,0); \
    f32x4 cz0b = __builtin_amdgcn_mfma_f32_16x16x32_bf16(ufrag[0][0][2], hf2, zero4, 0,0,0);\
    f32x4 cz1b = __builtin_amdgcn_mfma_f32_16x16x32_bf16(ufrag[0][1][2], hf2, zero4, 0,0,0);\
    f32x4 ch0b = __builtin_amdgcn_mfma_f32_16x16x32_bf16(ufrag[1][0][2], hf2, zero4, 0,0,0);\
    f32x4 ch1b = __builtin_amdgcn_mfma_f32_16x16x32_bf16(ufrag[1][1][2], hf2, zero4, 0,0,0);\
    cz0a = __builtin_amdgcn_mfma_f32_16x16x32_bf16(ufrag[0][0][1], hf1, cz0a, 0, 0, 0);     \
    cz1a = __builtin_amdgcn_mfma_f32_16x16x32_bf16(ufrag[0][1][1], hf1, cz1a, 0, 0, 0);     \
    ch0a = __builtin_amdgcn_mfma_f32_16x16x32_bf16(ufrag[1][0][1], hf1, ch0a, 0, 0, 0);     \
    ch1a = __builtin_amdgcn_mfma_f32_16x16x32_bf16(ufrag[1][1][1], hf1, ch1a, 0, 0, 0);     \
    cz0b = __builtin_amdgcn_mfma_f32_16x16x32_bf16(ufrag[0][0][3], hf3, cz0b, 0, 0, 0);     \
    cz1b = __builtin_amdgcn_mfma_f32_16x16x32_bf16(ufrag[0][1][3], hf3, cz1b, 0, 0, 0);     \
    ch0b = __builtin_amdgcn_mfma_f32_16x16x32_bf16(ufrag[1][0][3], hf3, ch0b, 0, 0, 0);     \
    ch1b = __builtin_amdgcn_mfma_f32_16x16x32_bf16(ufrag[1][1][3], hf3, ch1b, 0, 0, 0);     \
    /* ax for t+1 (independent; fills MFMA shadow) */                                       \
    axz0 = __builtin_amdgcn_mfma_f32_16x16x32_bf16(wfrag[0][0], xf, bias2[0][0], 0, 0, 0);  \
    axz1 = __builtin_amdgcn_mfma_f32_16x16x32_bf16(wfrag[0][1], xf, bias2[0][1], 0, 0, 0);  \
    axh0 = __builtin_amdgcn_mfma_f32_16x16x32_bf16(wfrag[1][0], xf, bias2[1][0], 0, 0, 0);  \
    axh1 = __builtin_amdgcn_mfma_f32_16x16x32_bf16(wfrag[1][1], xf, bias2[1][1], 0, 0, 0);  \
    const f32x4 az0 = cz0a + cz0b;                                                          \
    const f32x4 az1 = cz1a + cz1b;                                                          \
    const f32x4 ah0 = ch0a + ch0b;                                                          \
    const f32x4 ah1 = ch1a + ch1b;                                                          \
    f32x4 hn0 = gru_elem(az0, ah0, hv0);                                                    \
    f32x4 hn1 = gru_elem(az1, ah1, hv1);                                                    \
    hv0 = hn0; hv1 = hn1;                                                                   \
    /* publish bf16 h(t+1) to the other buffer (2 n-tiles per lane) */                      \
    hb[P ^ 1][4 * w + 0 + (g >> 1)][ml][g & 1] = pack4_bf16(hn0);                           \
    hb[P ^ 1][4 * w + 2 + (g >> 1)][ml][g & 1] = pack4_bf16(hn1);                           \
    /* stream hidden_seq[b, t, :] — stays in flight across the barrier */                   \
    __builtin_nontemporal_store(hn0, (f32x4*)optr);                                         \
    __builtin_nontemporal_store(hn1, (f32x4*)(optr + 16));                                  \
    optr += NH;                                                                             \
  }

  for (int chunk = 0; chunk < NS / 8; ++chunk) {
    const int  xb   = chunk & 1;
    const bool more = (chunk + 1 < NS / 8);
#pragma unroll
    for (int tt = 0; tt < 8; ++tt) {
      if (tt == 0 && more) {  // issue next chunk's x loads (~6 steps of cover)
        const float* p = xbase + (size_t)(chunk + 1) * (8 * NI);
        vx0 = *(const f32x4*)(p);
        vx1 = *(const f32x4*)(p + 4);
        vx2 = *(const f32x4*)(p + 8);
        vx3 = *(const f32x4*)(p + 12);
      }

      if (tt & 1) { GRU_STEP(1, xb, tt) } else { GRU_STEP(0, xb, tt) }

      if (tt == 6 && more) {  // convert + write next x chunk
        bf16x8 u0, u1;
#pragma unroll
        for (int j = 0; j < 4; ++j) {
          u0[j] = (__bf16)vx0[j]; u0[4 + j] = (__bf16)vx1[j];
          u1[j] = (__bf16)vx2[j]; u1[4 + j] = (__bf16)vx3[j];
        }
        *(bf16x8*)&hx[xb ^ 1][tt_st][ku0 + 0][r_st][0] = u0;
        *(bf16x8*)&hx[xb ^ 1][tt_st][ku0 + 1][r_st][0] = u1;
      }

      lds_barrier();   // lgkmcnt(0) + s_barrier only; no vmcnt drain
    }
  }

  // h_last
  const size_t lbase = (size_t)NB * NS * NH + (size_t)(rb + ml) * NH + 32 * w + 4 * g;
  *(f32x4*)(out + lbase)      = hv0;
  *(f32x4*)(out + lbase + 16) = hv1;
}

extern "C" void kernel_launch(void* const* d_in, const int* in_sizes, int n_in,
                              void* d_out, int out_size, void* d_ws, size_t ws_size,
                              hipStream_t stream) {
  const float* x  = (const float*)d_in[0];
  // d_in[1..3] = W_r, U_r, b_r: unused (r gate never affects the output)
  const float* Wz = (const float*)d_in[4];
  const float* Uz = (const float*)d_in[5];
  const float* bz = (const float*)d_in[6];
  const float* Wh = (const float*)d_in[7];
  const float* Uh = (const float*)d_in[8];
  const float* bh = (const float*)d_in[9];
  float* out = (float*)d_out;

  gru_scan<<<dim3(NB / 16), dim3(256), 0, stream>>>(x, Wz, Uz, bz, Wh, Uh, bh, out);
}